// Round 4
// baseline (438.951 us; speedup 1.0000x reference)
//
#include <hip/hip_runtime.h>

typedef unsigned short u16;
typedef short bf16x8 __attribute__((ext_vector_type(8)));
typedef float floatx4 __attribute__((ext_vector_type(4)));

// ---------- bf16 helpers (bit-level RNE) --------------------------------------
static __device__ __forceinline__ u16 f2bf(float f) {
  unsigned int u = __float_as_uint(f);
  unsigned int lsb = (u >> 16) & 1u;
  u += 0x7FFFu + lsb;                 // round-to-nearest-even
  return (u16)(u >> 16);
}
static __device__ __forceinline__ float bf2f(u16 u) {
  return __uint_as_float(((unsigned int)u) << 16);
}

// ---------- async global->LDS, 16B per lane (dest = uniform base + lane*16) ----
static __device__ __forceinline__ void gl_lds16(const u16* g, u16* l) {
  __builtin_amdgcn_global_load_lds(
      (const __attribute__((address_space(1))) void*)g,
      (__attribute__((address_space(3))) void*)l, 16, 0, 0);
}

// ---------- unified prep: weight transposes + bias concat + x split/transpose --
__global__ __launch_bounds__(256)
void prep_all(const float* __restrict__ wq, const float* __restrict__ wk,
              const float* __restrict__ wv, const float* __restrict__ wp,
              const float* __restrict__ bq, const float* __restrict__ bk,
              const float* __restrict__ x,
              u16* __restrict__ qkThi, u16* __restrict__ qkTlo,
              u16* __restrict__ wvThi, u16* __restrict__ wpThi,
              float* __restrict__ bqk,
              u16* __restrict__ xhi, u16* __restrict__ xlo,
              u16* __restrict__ xThi) {
  __shared__ float t[32][33];
  const int z = blockIdx.z;
  const int tid = threadIdx.x;
  const int lr = tid >> 3;            // 0..31
  const int lc = (tid & 7) * 4;       // 0,4,..,28

  if (z == 4) {
    if (blockIdx.y == 0 && blockIdx.x < 8) {
      const int i = blockIdx.x * 256 + tid;
      bqk[i] = (i < 1024) ? bq[i] : bk[i - 1024];
    }
    return;
  }

  if (z >= 5) {
    const int r0 = ((z - 5) * 32 + blockIdx.y) * 32;
    const int c0 = blockIdx.x * 32;
    float4 v = *(const float4*)(x + (size_t)(r0 + lr) * 1024 + c0 + lc);
    float f[4] = {v.x, v.y, v.z, v.w};
    t[lr][lc + 0] = v.x; t[lr][lc + 1] = v.y; t[lr][lc + 2] = v.z; t[lr][lc + 3] = v.w;
    u16 ph[4], pl[4];
#pragma unroll
    for (int j = 0; j < 4; j++) {
      ph[j] = f2bf(f[j]);
      pl[j] = f2bf(f[j] - bf2f(ph[j]));
    }
    const size_t o = (size_t)(r0 + lr) * 1024 + c0 + lc;
    *(uint2*)(xhi + o) = *(uint2*)ph;
    *(uint2*)(xlo + o) = *(uint2*)pl;
    __syncthreads();
    u16 pt[4];
#pragma unroll
    for (int j = 0; j < 4; j++) pt[j] = f2bf(t[lc + j][lr]);
    const int b = r0 >> 11, rt = r0 & 2047;
    *(uint2*)(xThi + (size_t)b * (1024 * 2048) + (size_t)(c0 + lr) * 2048 + rt + lc) =
        *(uint2*)pt;
    return;
  }

  // weight transposes (z 0..3)
  const float* in = (z == 0) ? wq : (z == 1) ? wk : (z == 2) ? wv : wp;
  u16* hi = (z == 2) ? wvThi : (z == 3) ? wpThi : (qkThi + (size_t)z * 1024 * 1024);
  u16* lo = (z == 0) ? qkTlo : (z == 1) ? (qkTlo + 1024 * 1024) : (u16*)nullptr;
  const int want_lo = (z < 2);

  const int r0 = blockIdx.y * 32, c0 = blockIdx.x * 32;
  float4 v = *(const float4*)(in + (size_t)(r0 + lr) * 1024 + c0 + lc);
  t[lr][lc + 0] = v.x; t[lr][lc + 1] = v.y; t[lr][lc + 2] = v.z; t[lr][lc + 3] = v.w;
  __syncthreads();
  u16 ph[4], pl[4];
#pragma unroll
  for (int j = 0; j < 4; j++) {
    float f = t[lc + j][lr];
    ph[j] = f2bf(f);
    if (want_lo) pl[j] = f2bf(f - bf2f(ph[j]));
  }
  const size_t o = (size_t)(c0 + lr) * 1024 + r0 + lc;
  *(uint2*)(hi + o) = *(uint2*)ph;
  if (want_lo) *(uint2*)(lo + o) = *(uint2*)pl;
}

// ---------- BMx256 pipelined GEMM (generalized R3 structure) -------------------
// C[M,N] = A.B^T (+ optional 3-term hi/lo split via K-extension when SPLIT=1:
// Ahi.Bhi^T + Ahi.Blo^T + Alo.Bhi^T, K=1024 per term, NP=96).
// NP = number of k-half(32) pairs; K_eff = NP*32. Runtime lda/ldb/ldc strides.
// Pipelining (R3-proven): phase 1 of pair H reads b23 (slot H, consumed phase 2
// under cluster-1 MFMA cover); phase 2 reads a[AF]+b01 of slot H+1 (consumed
// next pair's cluster 1 under cluster-2 cover). 1 barrier/pair. Even/odd reg
// sets avoid dyn indexing (rule #20); sched_barrier(0) pins issue order.
// LDS ring: 4 half-slots/operand; swizzle phys chunk = logical ^ ((row>>1)&3)
// (2-way = free, R2-verified 0 conflicts); source inverse-swizzled (rule #21).
// vmcnt: per-pair issues = 2 (B) + BM/128 (A); invariant "slot H+2 complete at
// end of pair H" -> steady vmcnt(VMS), VMS = BM/128 (A(H+3) stays in flight).
// BM=256: 8 waves of 128x64 (AF=8). BM=128: 8 waves of 64x64 (AF=4).
// OM: 0 bf16 out (*scale + bias), 2 fp32 out (*scale + bias),
//     5 QK-routed planar split: col<1024 -> C0/C1 else C2/C3 (ldc=1024 each).
template<int BM, int SPLIT, int OM, int HB>
__global__ __launch_bounds__(512, 2)
void gemm8(const u16* __restrict__ Ahi, const u16* __restrict__ Alo,
           const u16* __restrict__ Bhi, const u16* __restrict__ Blo,
           const float* __restrict__ bias,
           void* __restrict__ C0, void* __restrict__ C1,
           void* __restrict__ C2, void* __restrict__ C3,
           int lda, int ldb, int ldc, int NP,
           long long aB, long long bB, long long cB, float scale) {
  constexpr int AF = BM / 32;          // A frags per wave (8 or 4)
  constexpr int ASLOT = BM * 32;       // A half-slot elems
  constexpr int VMS = BM / 128;        // steady vmcnt (2 or 1)
  __shared__ __align__(16) u16 As[4 * ASLOT];
  __shared__ __align__(16) u16 Bs[4 * 8192];

  // bijective XCD swizzle on flattened id (nwg % 8 == 0 at all call sites)
  const int gx = gridDim.x, gy = gridDim.y, gz = gridDim.z;
  const int flat = blockIdx.x + gx * (blockIdx.y + gy * blockIdx.z);
  const int nwg = gx * gy * gz;
  const int lg = (flat & 7) * (nwg >> 3) + (flat >> 3);
  const int bx = lg % gx;
  const int by = (lg / gx) % gy;
  const int bz = lg / (gx * gy);

  const int m0 = by * BM, n0 = bx * 256;
  const u16* pAhi = Ahi + (size_t)bz * aB;
  const u16* pAlo = SPLIT ? (Alo + (size_t)bz * aB) : (const u16*)nullptr;
  const u16* pBhi = Bhi + (size_t)bz * bB;
  const u16* pBlo = SPLIT ? (Blo + (size_t)bz * bB) : (const u16*)nullptr;

  const int tid = threadIdx.x;
  const int w = tid >> 6;             // wave 0..7
  const int L = tid & 63;
  const int rr = L & 15, quad = L >> 4;
  const int wm = (w >> 2) * (BM / 2); // 2 row-blocks
  const int wn = (w & 3) * 64;        // 4 col-blocks

  // staging: lane covers row w*16 + (L>>2), phys chunk L&3; inverse-swizzled
  // global source chunk = (L&3) ^ s(row), s(row) = (row>>1)&3 = (L>>3)&3
  const int rbase = w * 16 + (L >> 2);
  const int coff = (((L & 3) ^ ((L >> 3) & 3)) << 3);
  const size_t arow = (size_t)(m0 + rbase) * lda + coff;
  const size_t brow = (size_t)(n0 + rbase) * ldb + coff;
  u16* const ldA = As + w * 512;      // wave-uniform LDS dest base
  u16* const ldB = Bs + w * 512;

  // frag reads: row*32 + (quad ^ ((row>>1)&3))*8 ; (row>>1)&3 == (rr>>1)&3
  const int aoff = ((wm + rr) << 5) + ((quad ^ ((rr >> 1) & 3)) << 3);
  const int boff = ((wn + rr) << 5) + ((quad ^ ((rr >> 1) & 3)) << 3);

  auto stageA = [&](int H) {
    const u16* src;
    int koff;
    if (SPLIT) {                      // K=1024/term: hh,hl -> Ahi; lh -> Alo
      const int kt = H >> 1;
      src = (kt < 32) ? pAhi : pAlo;
      koff = ((kt & 15) << 6) + ((H & 1) << 5);
    } else {
      src = pAhi;
      koff = H << 5;
    }
    const u16* g = src + arow + koff;
    u16* l = ldA + (H & 3) * ASLOT;
    gl_lds16(g, l);
    if (BM == 256) gl_lds16(g + (size_t)128 * lda, l + 4096);
  };
  auto stageB = [&](int H) {
    const u16* src;
    int koff;
    if (SPLIT) {                      // hh -> Bhi; hl -> Blo; lh -> Bhi
      const int kt = H >> 1;
      src = (kt < 16) ? pBhi : (kt < 32) ? pBlo : pBhi;
      koff = ((kt & 15) << 6) + ((H & 1) << 5);
    } else {
      src = pBhi;
      koff = H << 5;
    }
    const u16* g = src + brow + koff;
    u16* l = ldB + (H & 3) * 8192;
    gl_lds16(g, l);
    gl_lds16(g + (size_t)128 * ldb, l + 4096);
  };

  floatx4 acc[AF][4] = {};
  bf16x8 aE[AF], aO[AF], b01E[2], b01O[2], b23[2];

#define RD_SET(slot, A_, B_)                                                   \
  {                                                                            \
    const u16* ab_ = As + ((slot) & 3) * ASLOT + aoff;                         \
    const u16* bb_ = Bs + ((slot) & 3) * 8192 + boff;                          \
    _Pragma("unroll")                                                          \
    for (int i = 0; i < AF; i++) A_[i] = *(const bf16x8*)(ab_ + i * 512);      \
    B_[0] = *(const bf16x8*)(bb_);                                             \
    B_[1] = *(const bf16x8*)(bb_ + 512);                                       \
  }

#define PAIRX(H, AC, B01C, AN, B01N, SB2, SA3, RDN, VM)                        \
  {                                                                            \
    __builtin_amdgcn_sched_barrier(0);                                         \
    {                                                                          \
      const u16* bb_ = Bs + ((H) & 3) * 8192 + boff;                           \
      b23[0] = *(const bf16x8*)(bb_ + 1024);                                   \
      b23[1] = *(const bf16x8*)(bb_ + 1536);                                   \
    }                                                                          \
    if (SB2) stageB((H) + 2);                                                  \
    __builtin_amdgcn_sched_barrier(0);                                         \
    __builtin_amdgcn_s_setprio(1);                                             \
    _Pragma("unroll")                                                          \
    for (int i = 0; i < AF; i++) {                                             \
      acc[i][0] = __builtin_amdgcn_mfma_f32_16x16x32_bf16(AC[i], B01C[0], acc[i][0], 0, 0, 0); \
      acc[i][1] = __builtin_amdgcn_mfma_f32_16x16x32_bf16(AC[i], B01C[1], acc[i][1], 0, 0, 0); \
    }                                                                          \
    __builtin_amdgcn_s_setprio(0);                                             \
    __builtin_amdgcn_sched_barrier(0);                                         \
    if (RDN) RD_SET((H) + 1, AN, B01N);                                        \
    if (SA3) stageA((H) + 3);                                                  \
    __builtin_amdgcn_sched_barrier(0);                                         \
    __builtin_amdgcn_s_setprio(1);                                             \
    _Pragma("unroll")                                                          \
    for (int i = 0; i < AF; i++) {                                             \
      acc[i][2] = __builtin_amdgcn_mfma_f32_16x16x32_bf16(AC[i], b23[0], acc[i][2], 0, 0, 0); \
      acc[i][3] = __builtin_amdgcn_mfma_f32_16x16x32_bf16(AC[i], b23[1], acc[i][3], 0, 0, 0); \
    }                                                                          \
    __builtin_amdgcn_s_setprio(0);                                             \
    if ((VM) == 2) asm volatile("s_waitcnt vmcnt(2)");                         \
    else if ((VM) == 1) asm volatile("s_waitcnt vmcnt(1)");                    \
    else if ((VM) == 0) asm volatile("s_waitcnt vmcnt(0)");                    \
    __builtin_amdgcn_s_barrier();                                              \
  }

  // prologue: A0,B0,A1,B1,A2 in flight; vmcnt(VMS) completes slots 0,1
  stageA(0); stageB(0); stageA(1); stageB(1); stageA(2);
  if (VMS == 2) asm volatile("s_waitcnt vmcnt(2)");
  else          asm volatile("s_waitcnt vmcnt(1)");
  __builtin_amdgcn_s_barrier();
  RD_SET(0, aE, b01E);                // pair 0's cluster-1 operands

  for (int H = 0; H + 4 < NP; H += 2) {
    PAIRX(H,     aE, b01E, aO, b01O, true, true, true, VMS);
    PAIRX(H + 1, aO, b01O, aE, b01E, true, true, true, VMS);
  }
  {
    const int T = NP - 4;             // NP even; T even -> E parity
    PAIRX(T,     aE, b01E, aO, b01O, true,  true,  true,  VMS); // B(T+2), A(T+3)
    PAIRX(T + 1, aO, b01O, aE, b01E, true,  false, true,  0);   // B(T+3); drain
    PAIRX(T + 2, aE, b01E, aO, b01O, false, false, true,  -1);  // read slot T+3
    PAIRX(T + 3, aO, b01O, aE, b01E, false, false, false, -1);
  }
#undef PAIRX
#undef RD_SET

  // epilogue: D[row = quad*4+ii][col = rr] per 16x16 fragment (m89-verified)
#pragma unroll
  for (int i = 0; i < AF; i++) {
    const int mb = m0 + wm + i * 16 + quad * 4;
#pragma unroll
    for (int j = 0; j < 4; j++) {
      const int col = n0 + wn + j * 16 + rr;
      float bvs = 0.f;
      if (HB) bvs = bias[col];
      if (OM == 5) {
        u16* hi; u16* lo;
        if (col < 1024) { hi = (u16*)C0; lo = (u16*)C1; }
        else            { hi = (u16*)C2; lo = (u16*)C3; }
        const int cc = col & 1023;
#pragma unroll
        for (int ii = 0; ii < 4; ii++) {
          const float v = acc[i][j][ii] + bvs;
          const size_t idx = (size_t)(mb + ii) * 1024 + cc;
          const u16 h = f2bf(v);
          hi[idx] = h;
          lo[idx] = f2bf(v - bf2f(h));
        }
      } else if (OM == 0) {
        u16* Cb = (u16*)C0 + (size_t)bz * cB;
#pragma unroll
        for (int ii = 0; ii < 4; ii++) {
          const float v = acc[i][j][ii] * scale + bvs;
          Cb[(size_t)(mb + ii) * ldc + col] = f2bf(v);
        }
      } else {
        float* Cf = (float*)C0 + (size_t)bz * cB;
#pragma unroll
        for (int ii = 0; ii < 4; ii++)
          Cf[(size_t)(mb + ii) * ldc + col] = acc[i][j][ii] * scale + bvs;
      }
    }
  }
}

// ---------- row softmax over 2048 fp32 scores, in place + bf16 copy ------------
__global__ __launch_bounds__(256)
void softmax_rows(float* __restrict__ S, u16* __restrict__ Pb) {
  const int row = blockIdx.x;
  float* s = S + (size_t)row * 2048;
  const int tid = threadIdx.x;
  const int w = tid >> 6;
  __shared__ float redm[4];
  __shared__ float reds[4];

  float v[8];
  float mx = -1e30f;
#pragma unroll
  for (int i = 0; i < 8; i++) {
    v[i] = s[tid + 256 * i];
    mx = fmaxf(mx, v[i]);
  }
#pragma unroll
  for (int o = 32; o > 0; o >>= 1) mx = fmaxf(mx, __shfl_xor(mx, o, 64));
  if ((tid & 63) == 0) redm[w] = mx;
  __syncthreads();
  mx = fmaxf(fmaxf(redm[0], redm[1]), fmaxf(redm[2], redm[3]));

  float sum = 0.f;
#pragma unroll
  for (int i = 0; i < 8; i++) {
    v[i] = __expf(v[i] - mx);
    sum += v[i];
  }
#pragma unroll
  for (int o = 32; o > 0; o >>= 1) sum += __shfl_xor(sum, o, 64);
  if ((tid & 63) == 0) reds[w] = sum;
  __syncthreads();
  sum = reds[0] + reds[1] + reds[2] + reds[3];
  const float rs = 1.0f / sum;
#pragma unroll
  for (int i = 0; i < 8; i++) {
    const float p = v[i] * rs;
    s[tid + 256 * i] = p;
    Pb[(size_t)row * 2048 + tid + 256 * i] = f2bf(p);
  }
}

// ---------- launch ------------------------------------------------------------
extern "C" void kernel_launch(void* const* d_in, const int* in_sizes, int n_in,
                              void* d_out, int out_size, void* d_ws, size_t ws_size,
                              hipStream_t stream) {
  const float* x  = (const float*)d_in[0];
  const float* wq = (const float*)d_in[1];
  const float* bq = (const float*)d_in[2];
  const float* wk = (const float*)d_in[3];
  const float* bk = (const float*)d_in[4];
  const float* wv = (const float*)d_in[5];
  const float* bv = (const float*)d_in[6];
  const float* wp = (const float*)d_in[7];
  const float* bp = (const float*)d_in[8];

  const size_t MB = 1024 * 1024;
  char* ws = (char*)d_ws;
  u16* qkThi = (u16*)(ws + 0 * MB);          // [2048][1024] bf16, 4 MB
  u16* qkTlo = (u16*)(ws + 4 * MB);          // 4 MB
  u16* wvThi = (u16*)(ws + 8 * MB);          // 2 MB
  u16* wpThi = (u16*)(ws + 10 * MB);         // 2 MB
  float* bqk = (float*)(ws + 12 * MB);       // 8 KB
  u16* xhi   = (u16*)(ws + 13 * MB);         // 16 MB each (8192x1024 bf16)
  u16* xlo   = (u16*)(ws + 29 * MB);
  u16* qhi   = (u16*)(ws + 45 * MB);
  u16* qlo   = (u16*)(ws + 61 * MB);
  u16* khi   = (u16*)(ws + 77 * MB);
  u16* klo   = (u16*)(ws + 93 * MB);
  u16* xThi  = (u16*)(ws + 109 * MB);        // [b][1024][2048] bf16, 16 MB
  u16* pbf   = khi;                          // overlay: k dead after scores
  u16* px    = qhi;                          // overlay: q dead after scores
  u16* ctx   = qlo;                          // overlay

  float* outp = (float*)d_out;               // [4,2048,1024] fp32
  float* scf  = (float*)d_out + 8388608;     // scores -> softmax in place

  // prep: weights + bias + x split/transpose, one launch
  prep_all<<<dim3(32, 32, 13), dim3(256), 0, stream>>>(
      wq, wk, wv, wp, bq, bk, x, qkThi, qkTlo, wvThi, wpThi, bqk, xhi, xlo, xThi);

  // fused Q|K projection: 256^2 pipelined, K-extended 3-term split, routed
  // planar split outputs. 256 blocks = 1/CU.
  gemm8<256, 1, 5, 1><<<dim3(8, 32, 1), dim3(512), 0, stream>>>(
      xhi, xlo, qkThi, qkTlo, bqk, qhi, qlo, khi, klo,
      1024, 1024, 1024, 96, 0, 0, 0, 1.0f);

  // scores = (q . k) * 32, 256^2 pipelined, fp32 into d_out's p region
  gemm8<256, 1, 2, 0><<<dim3(8, 8, 4), dim3(512), 0, stream>>>(
      qhi, qlo, khi, klo, nullptr, scf, nullptr, nullptr, nullptr,
      1024, 1024, 2048, 96, 2048LL * 1024, 2048LL * 1024, 2048LL * 2048, 32.0f);

  // softmax rows: fp32 p in place (d_out) + bf16 p
  softmax_rows<<<dim3(8192), dim3(256), 0, stream>>>(scf, pbf);

  // px = p @ x  (reassociation: ctx = (p@x)@wv + bv since rows of p sum to 1)
  // 128x256 pipelined, 256 blocks.
  gemm8<128, 0, 0, 0><<<dim3(4, 16, 4), dim3(512), 0, stream>>>(
      pbf, nullptr, xThi, nullptr, nullptr, px, nullptr, nullptr, nullptr,
      2048, 2048, 1024, 64, 2048LL * 2048, 1024LL * 2048, 2048LL * 1024, 1.0f);

  // ctx = px @ wv + bv (bf16 out), 128x256 pipelined, 256 blocks
  gemm8<128, 0, 0, 1><<<dim3(4, 64, 1), dim3(512), 0, stream>>>(
      px, nullptr, wvThi, nullptr, bv, ctx, nullptr, nullptr, nullptr,
      1024, 1024, 1024, 32, 0, 0, 0, 1.0f);

  // output = ctx @ wp + bp, fp32 out, 128x256 pipelined, 256 blocks
  gemm8<128, 0, 2, 1><<<dim3(4, 64, 1), dim3(512), 0, stream>>>(
      ctx, nullptr, wpThi, nullptr, bp, outp, nullptr, nullptr, nullptr,
      1024, 1024, 1024, 32, 0, 0, 0, 1.0f);
}